// Round 11
// baseline (296.548 us; speedup 1.0000x reference)
//
#include <hip/hip_runtime.h>
#include <math.h>

#define B_ 8
#define S_ 1024
#define D_ 1024
#define H_ 16
#define DK_ 64
#define EPS_ 1e-5f

typedef __bf16 bf16_t;
typedef __bf16 bf16x8 __attribute__((ext_vector_type(8)));
typedef __bf16 bf16x4v __attribute__((ext_vector_type(4)));
typedef float  f32x4  __attribute__((ext_vector_type(4)));

__device__ __forceinline__ void gld16(const void* g, void* l) {
    __builtin_amdgcn_global_load_lds(
        (const __attribute__((address_space(1))) void*)g,
        (__attribute__((address_space(3))) void*)l, 16, 0, 0);
}

// ---------------------------------------------------------------------------
// prep: weight transpose+convert+PACK (z=0..4) and x f32->bf16 (z=5..36).
// B-pack layout: elem(n,k) -> [n>>4][k>>3][n&15][k&7]; a wave's MFMA B-frag
// (16 n x 8 k) is 1 KB contiguous -> one coalesced b128 load, no B LDS.
// ---------------------------------------------------------------------------
__global__ __launch_bounds__(256)
void prep(const float* __restrict__ x,
          const float* __restrict__ Wq, const float* __restrict__ Wk,
          const float* __restrict__ Wv, const float* __restrict__ W1,
          const float* __restrict__ W2, bf16_t* __restrict__ xb,
          bf16_t* __restrict__ WtQKV, bf16_t* __restrict__ Wt1,
          bf16_t* __restrict__ Wt2)
{
    __shared__ float tile[64][65];
    const int tid = threadIdx.x;
    const int z = blockIdx.z;

    if (z >= 5) {   // x convert
        const int blk = (z - 5) * 256 + blockIdx.y * 16 + blockIdx.x;
        const int i = (blk * 256 + tid) * 4;
        const float4 v = *(const float4*)(x + i);
        bf16x4v o = { (bf16_t)v.x, (bf16_t)v.y, (bf16_t)v.z, (bf16_t)v.w };
        *(bf16x4v*)(xb + i) = o;
        return;
    }

    const int n0 = blockIdx.x * 64, k0 = blockIdx.y * 64;
    const int col = tid & 63, r0 = tid >> 6;
    const float* src = (z == 0) ? Wq : (z == 1) ? Wk : (z == 2) ? Wv
                     : (z == 3) ? W1 : W2;
    #pragma unroll
    for (int i = 0; i < 16; i++) {
        const int row = r0 + i * 4;
        float v;
        if (z < 3)
            v = src[((size_t)(n0 >> 6) << 16) + (size_t)(k0 + row) * 64 + col];
        else
            v = src[(size_t)(k0 + row) * D_ + n0 + col];
        tile[row][col] = v;   // tile[a][b] = elem(k = k0+a, n = n0+b)
    }
    __syncthreads();
    bf16_t* dst = (z < 3) ? (WtQKV + (size_t)z * D_ * D_)
                : (z == 3) ? Wt1 : Wt2;
    // vectorized packed store: unit u = (n-row nr, k-chunk c); 16B contiguous.
    #pragma unroll
    for (int uu = 0; uu < 2; uu++) {
        const int u = uu * 256 + tid;
        const int nr = u >> 3, c = u & 7;
        const int n = n0 + nr, kk = k0 + c * 8;
        bf16x8 pkv;
        #pragma unroll
        for (int e = 0; e < 8; e++) pkv[e] = (bf16_t)tile[c * 8 + e][nr];
        *(bf16x8*)(dst + ((size_t)(n >> 4) * (D_ >> 3) + (kk >> 3)) * 128
                   + (size_t)(n & 15) * 8) = pkv;
    }
}

// ---------------------------------------------------------------------------
// 128x128 bf16 MFMA GEMM: A via LDS (3-buffer rotation, global_load_lds),
// B direct to registers from packed layout. Masked m-tile skip (R9).
// R10 post-mortem: skip cut average work (FETCH 92->65 MB) but NOT makespan —
//   QKV grid = 1536 blocks on 768 slots = 2 rounds; critical-path CUs got
//   two non-skipped blocks back-to-back. R11: LPT dispatch ordering —
//   always-working m-tiles (rows 0..511 per batch; len>=512 guarantees work)
//   get LOW block ids, maybe-masked tiles (rows 512..1023, ascending) get
//   HIGH ids. Short/skip blocks then backfill the drain tail instead of
//   punching idle bubbles mid-schedule. XCD-chunked swizzle preserved
//   WITHIN each set (set sizes 768/256 are %8==0 -> bijective).
// ---------------------------------------------------------------------------
template<int EPI, typename OUT>
__global__ __launch_bounds__(256, 3)
void gemm_bp(const bf16_t* __restrict__ A, const bf16_t* __restrict__ Bp,
             const float* __restrict__ bias, const int* __restrict__ lens,
             OUT* __restrict__ C, bf16_t* __restrict__ VTout,
             int M, int N, int NC, int K)
{
    __shared__ __align__(16) bf16_t As[3][128 * 64];

    const int tid  = threadIdx.x;
    const int lane = tid & 63;
    const int w    = tid >> 6;
    const int quad = lane >> 4, l16 = lane & 15;
    const int wm = w & 1, wn = w >> 1;
    const int sw8 = l16 & 7;

    // ---- LPT + XCD-chunked block mapping ----
    // set 0 (low ids): m-tiles with (row%1024) < 512  -> never masked.
    // set 1 (high ids): rows 512..1023, ascending mb  -> maybe masked (skip).
    const int nnt  = gridDim.x;
    const int flat = blockIdx.y * gridDim.x + blockIdx.x;
    const int half = (gridDim.x * gridDim.y) >> 1;   // 768 (QKV) / 256 (fc)
    const int set  = (flat >= half) ? 1 : 0;
    const int idx  = flat - set * half;
    const int swz  = (idx & 7) * (half >> 3) + (idx >> 3);   // XCD chunk, bijective
    const int mis  = swz / nnt;          // 0..(M/256)-1 : (batch, local-mb)
    const int nt   = swz % nnt;
    const int bm   = ((mis >> 2) * 8 + set * 4 + (mis & 3)) * 128;
    const int bn   = nt * 128;

    // ---- masked m-tile skip (block-uniform) ----
    if (lens != nullptr && (bm & (S_ - 1)) >= lens[bm >> 10]) {
        const uint4 zz = {0u, 0u, 0u, 0u};
        if (EPI == 0 && bn >= 2048) {
            // VT zero: 128 d-rows x 128 tokens (256 B/row), 2048 uint4 total.
            const int bb = bm >> 10, s0 = bm & 1023;
            #pragma unroll
            for (int u = 0; u < 8; u++) {
                const int idx2 = u * 256 + tid;
                const int row = idx2 >> 4, c = idx2 & 15;
                *(uint4*)(VTout + ((size_t)bb * 1024 + (bn - 2048) + row) * 1024
                          + s0 + c * 8) = zz;
            }
        } else {
            // C zero: 128 rows x 128 cols of OUT at stride NC.
            constexpr int UPR = (128 * sizeof(OUT)) / 16;   // uint4 per row
            #pragma unroll
            for (int u = 0; u < (128 * UPR) / 256; u++) {
                const int idx2 = u * 256 + tid;
                const int row = idx2 / UPR, c = idx2 % UPR;
                *(uint4*)((char*)(C + (size_t)(bm + row) * NC + bn) + c * 16) = zz;
            }
        }
        return;
    }

    const int rS  = tid >> 3;
    const int cS  = ((tid & 7) ^ (rS & 7)) << 3;
    const int dOf = w * 1024;

    const size_t ntStride = (size_t)(K >> 3) * 128;
    const bf16_t* Bw = Bp + ((size_t)(bn >> 4) + (size_t)wn * 4) * ntStride
                          + (size_t)quad * 128 + (size_t)l16 * 8;

    f32x4 acc[4][4];
    #pragma unroll
    for (int i = 0; i < 4; i++)
        #pragma unroll
        for (int j = 0; j < 4; j++)
            #pragma unroll
            for (int r = 0; r < 4; r++) acc[i][j][r] = 0.f;

#define SA(b_, kt_) { \
    _Pragma("unroll") \
    for (int s_ = 0; s_ < 4; s_++) \
        gld16(A + (size_t)(bm + s_ * 32 + rS) * K + (kt_) * 64 + cS, \
              (char*)As[b_] + s_ * 4096 + dOf); }
#define LB(dst_, kt_) { \
    _Pragma("unroll") \
    for (int j_ = 0; j_ < 4; j_++) \
        _Pragma("unroll") \
        for (int kh_ = 0; kh_ < 2; kh_++) \
            dst_[j_][kh_] = *(const bf16x8*)(Bw + (size_t)j_ * ntStride \
                                             + ((kt_) * 8 + kh_ * 4) * 128); }
#define KSTEP(cb_, sb_, BC_, BX_, t_) { \
    const int ktn_ = ((t_) + 1 < NKT) ? (t_) + 1 : NKT - 1; \
    const int kt2_ = ((t_) + 2 < NKT) ? (t_) + 2 : NKT - 1; \
    SA(sb_, kt2_); \
    LB(BX_, ktn_); \
    __builtin_amdgcn_sched_barrier(0); \
    const bf16_t* Ac = As[cb_]; \
    _Pragma("unroll") \
    for (int kh_ = 0; kh_ < 2; kh_++) { \
        bf16x8 a_[4]; \
        _Pragma("unroll") \
        for (int i_ = 0; i_ < 4; i_++) \
            a_[i_] = *(const bf16x8*)&Ac[(wm * 64 + i_ * 16 + l16) * 64 \
                                         + (((kh_ * 4 + quad) ^ sw8) << 3)]; \
        _Pragma("unroll") \
        for (int i_ = 0; i_ < 4; i_++) \
            _Pragma("unroll") \
            for (int j_ = 0; j_ < 4; j_++) \
                acc[i_][j_] = __builtin_amdgcn_mfma_f32_16x16x32_bf16( \
                    a_[i_], BC_[j_][kh_], acc[i_][j_], 0, 0, 0); \
    } \
    __builtin_amdgcn_sched_barrier(0); \
    asm volatile("s_waitcnt vmcnt(12)" ::: "memory"); \
    __builtin_amdgcn_s_barrier(); }

    const int NKT = K >> 6;   // 16 here (even; unroll-2 loop)

    bf16x8 bA[4][2], bB[4][2];
    SA(0, 0);                  // A(0) -> buf 0
    SA(1, 1);                  // A(1) -> buf 1
    LB(bA, 0);                 // B(0) -> regs
    asm volatile("s_waitcnt vmcnt(12)" ::: "memory");   // A(0) landed
    __builtin_amdgcn_s_barrier();

    int cb = 0;
    for (int t = 0; t < NKT; t += 2) {
        const int sb0 = cb ? cb - 1 : 2;          // (cb+2)%3
        KSTEP(cb, sb0, bA, bB, t);
        const int cb1 = (cb + 1 == 3) ? 0 : cb + 1;
        const int sb1 = cb1 ? cb1 - 1 : 2;
        KSTEP(cb1, sb1, bB, bA, t + 1);
        cb = (cb1 + 1 == 3) ? 0 : cb1 + 1;
    }

#undef SA
#undef LB
#undef KSTEP

    // ---- epilogue ----
    if (EPI == 0 && bn >= 2048) {
        // V block: transposed store into VT[(n-2048)][tok], 8B per (i,j).
        #pragma unroll
        for (int i = 0; i < 4; i++) {
            const int m0 = bm + wm * 64 + i * 16 + quad * 4;   // 4-aligned
            const int bb = m0 >> 10, s0 = m0 & 1023;
            #pragma unroll
            for (int j = 0; j < 4; j++) {
                const int n = bn + wn * 64 + j * 16 + l16;
                bf16x4v vv;
                #pragma unroll
                for (int r = 0; r < 4; r++) vv[r] = (bf16_t)acc[i][j][r];
                *(bf16x4v*)(VTout + ((size_t)bb * 1024 + (n - 2048)) * 1024 + s0) = vv;
            }
        }
        return;
    }
    #pragma unroll
    for (int i = 0; i < 4; i++) {
        #pragma unroll
        for (int r = 0; r < 4; r++) {
            const int m = bm + wm * 64 + i * 16 + quad * 4 + r;
            float keep = 1.f;
            if (EPI != 0) {
                const int s = m & (S_ - 1);
                const int bb = m >> 10;
                keep = (s < lens[bb]) ? 1.f : 0.f;
            }
            #pragma unroll
            for (int j = 0; j < 4; j++) {
                const int n = bn + wn * 64 + j * 16 + l16;
                float v = acc[i][j][r];
                if (EPI != 0) {
                    v += bias[n];
                    if (EPI == 1) v = fmaxf(v, 0.f);
                    v *= keep;
                }
                C[(size_t)m * NC + n] = (OUT)v;
            }
        }
    }
}

// ---------------------------------------------------------------------------
// bf16 MFMA flash attention, S^T formulation — R7 structure: V^T staged via
// DMA (pre-transposed by the QKV GEMM), K and V^T staged identically with
// chunk-XOR swizzle; no in-kernel transpose, conflicts ~0.
// ---------------------------------------------------------------------------
__global__ __launch_bounds__(512, 6)
void attn_mfma(const bf16_t* __restrict__ QK, const bf16_t* __restrict__ VT,
               const int* __restrict__ lens, bf16_t* __restrict__ Z)
{
    __shared__ __align__(16) bf16_t Ks[2][64][64];   // [buf][key][d], chunk-swizzled
    __shared__ __align__(16) bf16_t Vs[2][64][64];   // [buf][d][tok], chunk-swizzled
    __shared__ __align__(16) bf16_t Ps[128][72];     // [q][key], wave-private rows

    const int tid  = threadIdx.x;
    const int lane = tid & 63;
    const int w    = tid >> 6;          // 0..7
    const int quad = lane >> 4;
    const int l16  = lane & 15;
    const int id   = blockIdx.x;
    const int b    = id & 7;
    const int h    = (id >> 3) & 15;
    const int qt   = id >> 7;           // 0..7
    const int len  = lens[b];
    const int qbase = qt * 128;
    const bf16_t* Qp  = QK + (size_t)b * S_ * 2048 + (size_t)h * 64;
    const bf16_t* Kp  = Qp + 1024;
    const bf16_t* Vtp = VT + ((size_t)b * 16 + h) * 64 * 1024;  // [64 d][1024 tok]
    const size_t zbase = (size_t)b * S_ * D_ + (size_t)h * 64;

    if (qbase >= len) {   // fully masked query tile -> zeros (bf16)
        const int r = tid >> 2, c0 = (tid & 3) * 16;
        bf16_t* zp = Z + zbase + (size_t)(qbase + r) * D_ + c0;
        uint4 zz = {0u, 0u, 0u, 0u};
        *(uint4*)zp = zz;
        *(uint4*)(zp + 8) = zz;
        return;
    }

    // Q B-frags, fixed for the whole kernel: B[k=d=quad*8+j][n=q=l16]
    const int qrow = qbase + w * 16 + l16;
    const bf16x8 bq0 = *(const bf16x8*)(Qp + (size_t)qrow * 2048 + quad * 8);
    const bf16x8 bq1 = *(const bf16x8*)(Qp + (size_t)qrow * 2048 + 32 + quad * 8);

    // staging geometry (K and V^T alike): row sr = tid>>3 (0..63); source
    // chunk = (tid&7) ^ (sr&7); LDS linear dest (thread tid -> byte tid*16).
    const int sr = tid >> 3;
    const int sc = ((tid & 7) ^ (sr & 7)) << 3;

    f32x4 o[4];
    #pragma unroll
    for (int dm = 0; dm < 4; dm++)
        #pragma unroll
        for (int r = 0; r < 4; r++) o[dm][r] = 0.f;
    float l_q = 0.f;

    const int ntiles = (len + 63) >> 6;

    // ---- prologue: stage K(0), V^T(0) ----
    gld16(Kp  + (size_t)sr * 2048 + sc, (char*)&Ks[0][0][0] + w * 1024);
    gld16(Vtp + (size_t)sr * 1024 + sc, (char*)&Vs[0][0][0] + w * 1024);
    __syncthreads();

    for (int t = 0; t < ntiles; t++) {
        const int k0 = t * 64;
        const int cb = t & 1, nb = (t + 1) & 1;
        const int kn0 = (t + 1 < ntiles ? t + 1 : t) * 64;

        // ---- issue DMA prefetch for tile t+1 ----
        gld16(Kp  + (size_t)(kn0 + sr) * 2048 + sc, (char*)&Ks[nb][0][0] + w * 1024);
        gld16(Vtp + (size_t)sr * 1024 + kn0 + sc,   (char*)&Vs[nb][0][0] + w * 1024);
        __builtin_amdgcn_sched_barrier(0);

        // ---- S^T = K Q^T from Ks[cb], exp, stage P ----
        #pragma unroll
        for (int kt = 0; kt < 4; kt++) {
            const int r = kt * 16 + l16;           // r&7 == l16&7
            const bf16x8 ak0 = *(const bf16x8*)&Ks[cb][r][(quad ^ (l16 & 7)) << 3];
            const bf16x8 ak1 = *(const bf16x8*)&Ks[cb][r][((4 + quad) ^ (l16 & 7)) << 3];
            f32x4 z4 = {0.f, 0.f, 0.f, 0.f};
            z4 = __builtin_amdgcn_mfma_f32_16x16x32_bf16(ak0, bq0, z4, 0, 0, 0);
            const f32x4 sfv = __builtin_amdgcn_mfma_f32_16x16x32_bf16(ak1, bq1, z4, 0, 0, 0);
            bf16x4v pk;
            #pragma unroll
            for (int r2 = 0; r2 < 4; r2++) {
                const int key = k0 + kt * 16 + quad * 4 + r2;
                float p = __expf(sfv[r2] * 0.125f);
                p = (key < len) ? p : 0.f;
                l_q += p;
                pk[r2] = (bf16_t)p;
            }
            *(bf16x4v*)&Ps[w * 16 + l16][kt * 16 + quad * 4] = pk;
        }

        __syncthreads();   // bar1: K/V(t+1) DMA drained, Ps rows complete

        // ---- O^T += V^T P^T from Vs[cb] ----
        const bf16x8 bp0 = *(const bf16x8*)&Ps[w * 16 + l16][quad * 8];
        const bf16x8 bp1 = *(const bf16x8*)&Ps[w * 16 + l16][32 + quad * 8];
        #pragma unroll
        for (int dm = 0; dm < 4; dm++) {
            const int vr = dm * 16 + l16;          // vr&7 == l16&7
            const bf16x8 av0 = *(const bf16x8*)&Vs[cb][vr][(quad ^ (l16 & 7)) << 3];
            const bf16x8 av1 = *(const bf16x8*)&Vs[cb][vr][((4 + quad) ^ (l16 & 7)) << 3];
            o[dm] = __builtin_amdgcn_mfma_f32_16x16x32_bf16(av0, bp0, o[dm], 0, 0, 0);
            o[dm] = __builtin_amdgcn_mfma_f32_16x16x32_bf16(av1, bp1, o[dm], 0, 0, 0);
        }

        // bar2: all waves done reading Vs[cb]/Ks[cb] before next-iter DMA
        // re-targets buffer cb.
        __builtin_amdgcn_sched_barrier(0);
        __builtin_amdgcn_s_barrier();
        __builtin_amdgcn_sched_barrier(0);
    }

    // ---- final l reduce + epilogue ----
    l_q += __shfl_xor(l_q, 16);
    l_q += __shfl_xor(l_q, 32);
    const int qg = qbase + w * 16 + l16;
    const float inv = (qg < len) ? 1.f / l_q : 0.f;
    bf16_t* zrow = Z + zbase + (size_t)qg * D_;
    #pragma unroll
    for (int dm = 0; dm < 4; dm++) {
        bf16x4v st;
        #pragma unroll
        for (int r = 0; r < 4; r++) st[r] = (bf16_t)(o[dm][r] * inv);
        *(bf16x4v*)(zrow + dm * 16 + quad * 4) = st;
    }
}

// ---------------------------------------------------------------------------
// Residual-add + LayerNorm, D=1024, one block per row.
// ---------------------------------------------------------------------------
__device__ __forceinline__ void ln_core(float vx, float vy, float vz, float vw,
                                        int tid, float& mean, float& rstd)
{
    __shared__ float red[8];
    float s = vx + vy + vz + vw;
    #pragma unroll
    for (int off = 32; off; off >>= 1) s += __shfl_xor(s, off, 64);
    const int wv = tid >> 6, lane = tid & 63;
    if (lane == 0) red[wv] = s;
    __syncthreads();
    mean = (red[0] + red[1] + red[2] + red[3]) * (1.f / D_);
    const float dx = vx - mean, dy = vy - mean, dz = vz - mean, dw = vw - mean;
    float s2 = dx * dx + dy * dy + dz * dz + dw * dw;
    #pragma unroll
    for (int off = 32; off; off >>= 1) s2 += __shfl_xor(s2, off, 64);
    if (lane == 0) red[4 + wv] = s2;
    __syncthreads();
    rstd = rsqrtf((red[4] + red[5] + red[6] + red[7]) * (1.f / D_) + EPS_);
}

__global__ __launch_bounds__(256)
void add_ln1(const float* __restrict__ X, const bf16_t* __restrict__ Y,
             const float* __restrict__ g, const float* __restrict__ beta,
             bf16_t* __restrict__ out)
{
    const int row = blockIdx.x, tid = threadIdx.x;
    const float4 xv = ((const float4*)(X + (size_t)row * D_))[tid];
    const bf16x4v yv = *(const bf16x4v*)(Y + (size_t)row * D_ + tid * 4);
    const float vx = xv.x + (float)yv[0], vy = xv.y + (float)yv[1];
    const float vz = xv.z + (float)yv[2], vw = xv.w + (float)yv[3];
    float mean, rstd;
    ln_core(vx, vy, vz, vw, tid, mean, rstd);
    const float4 gv = ((const float4*)g)[tid];
    const float4 bv = ((const float4*)beta)[tid];
    bf16x4v o;
    o[0] = (bf16_t)((vx - mean) * rstd * gv.x + bv.x);
    o[1] = (bf16_t)((vy - mean) * rstd * gv.y + bv.y);
    o[2] = (bf16_t)((vz - mean) * rstd * gv.z + bv.z);
    o[3] = (bf16_t)((vw - mean) * rstd * gv.w + bv.w);
    *(bf16x4v*)(out + (size_t)row * D_ + tid * 4) = o;
}

__global__ __launch_bounds__(256)
void add_ln2(const bf16_t* __restrict__ X, const float* __restrict__ Y,
             const float* __restrict__ g, const float* __restrict__ beta,
             float* __restrict__ out)
{
    const int row = blockIdx.x, tid = threadIdx.x;
    const bf16x4v xv = *(const bf16x4v*)(X + (size_t)row * D_ + tid * 4);
    const float4 yv = ((const float4*)(Y + (size_t)row * D_))[tid];
    const float vx = (float)xv[0] + yv.x, vy = (float)xv[1] + yv.y;
    const float vz = (float)xv[2] + yv.z, vw = (float)xv[3] + yv.w;
    float mean, rstd;
    ln_core(vx, vy, vz, vw, tid, mean, rstd);
    const float4 gv = ((const float4*)g)[tid];
    const float4 bv = ((const float4*)beta)[tid];
    float4 o;
    o.x = (vx - mean) * rstd * gv.x + bv.x;
    o.y = (vy - mean) * rstd * gv.y + bv.y;
    o.z = (vz - mean) * rstd * gv.z + bv.z;
    o.w = (vw - mean) * rstd * gv.w + bv.w;
    ((float4*)(out + (size_t)row * D_))[tid] = o;
}

// ---------------------------------------------------------------------------
extern "C" void kernel_launch(void* const* d_in, const int* in_sizes, int n_in,
                              void* d_out, int out_size, void* d_ws, size_t ws_size,
                              hipStream_t stream)
{
    const float* x    = (const float*)d_in[0];
    const float* Wq   = (const float*)d_in[1];
    const float* Wk   = (const float*)d_in[2];
    const float* Wv   = (const float*)d_in[3];
    const float* fc1w = (const float*)d_in[4];
    const float* fc1b = (const float*)d_in[5];
    const float* fc2w = (const float*)d_in[6];
    const float* fc2b = (const float*)d_in[7];
    const float* ln1w = (const float*)d_in[8];
    const float* ln1b = (const float*)d_in[9];
    const float* ln2w = (const float*)d_in[10];
    const float* ln2b = (const float*)d_in[11];
    const int*   lens = (const int*)d_in[12];
    float* out = (float*)d_out;

    char* ws = (char*)d_ws;
    const size_t MB = 1024 * 1024;
    bf16_t* QKb   = (bf16_t*)(ws);              // 32 MB: [8192][2048] (Q,K)
    bf16_t* VTb   = (bf16_t*)(ws + 32 * MB);    // 16 MB: [8*16*64][1024] (V^T)
    bf16_t* Zb    = (bf16_t*)(ws + 48 * MB);    // 16 MB: [8192][1024] bf16
    bf16_t* X1b   = (bf16_t*)(ws + 80 * MB);    // 16 MB
    bf16_t* xb    = (bf16_t*)(ws + 96 * MB);    // 16 MB (dead after QKV)
    bf16_t* H1b   = (bf16_t*)(ws + 96 * MB);    //   reuses xb slot
    float*  FF    = (float*)(ws + 48 * MB);     //   reuses Zb slot (32 MB)
    bf16_t* WtQKV = (bf16_t*)(ws + 112 * MB);   // 6 MB (packed)
    bf16_t* Wt1   = (bf16_t*)(ws + 118 * MB);   // 2 MB (packed)
    bf16_t* Wt2   = (bf16_t*)(ws + 120 * MB);   // 2 MB (packed)

    const int M = B_ * S_;

    prep<<<dim3(16, 16, 37), 256, 0, stream>>>(x, Wq, Wk, Wv, fc1w, fc2w,
                                               xb, WtQKV, Wt1, Wt2);

    gemm_bp<0, bf16_t><<<dim3(3072 / 128, M / 128), 256, 0, stream>>>(
        xb, WtQKV, nullptr, lens, QKb, VTb, M, 3072, 2048, D_);

    attn_mfma<<<dim3(1024), 512, 0, stream>>>(QKb, VTb, lens, Zb);

    add_ln1<<<M, 256, 0, stream>>>(x, Zb, ln1w, ln1b, X1b);

    gemm_bp<1, bf16_t><<<dim3(D_ / 128, M / 128), 256, 0, stream>>>(
        X1b, Wt1, fc1b, lens, H1b, nullptr, M, D_, D_, D_);
    gemm_bp<2, float><<<dim3(D_ / 128, M / 128), 256, 0, stream>>>(
        H1b, Wt2, fc2b, lens, FF, nullptr, M, D_, D_, D_);

    add_ln2<<<M, 256, 0, stream>>>(X1b, FF, ln2w, ln2b, out);
}